// Round 7
// baseline (7397.967 us; speedup 1.0000x reference)
//
#include <hip/hip_runtime.h>
#include <hip/hip_fp16.h>
#include <math.h>

#define Bn 32
#define Tn 64
#define Fdim 32
#define Gdim 32
#define Hdim 256
#define Ndim 20000
#define Cdim 32
#define G4 1024      // 4*H
#define BT 2048      // B*T
#define EPSc 1e-5f

__device__ __forceinline__ float sigmoidf_(float x){ return 1.0f/(1.0f + __expf(-x)); }
__device__ __forceinline__ float tanhf_(float x){ return 2.0f/(1.0f+__expf(-2.0f*x)) - 1.0f; }

typedef _Float16 h2t __attribute__((ext_vector_type(2)));

__device__ __forceinline__ float fdot2_(unsigned w, unsigned h, float acc){
#if defined(__has_builtin) && __has_builtin(__builtin_amdgcn_fdot2)
  return __builtin_amdgcn_fdot2(__builtin_bit_cast(h2t, w), __builtin_bit_cast(h2t, h), acc, false);
#else
  h2t a = __builtin_bit_cast(h2t, w), b = __builtin_bit_cast(h2t, h);
  acc = fmaf((float)a.x, (float)b.x, acc);
  return fmaf((float)a.y, (float)b.y, acc);
#endif
}

__device__ __forceinline__ unsigned packh_(float lo, float hi){
  unsigned ulo = (unsigned)__half_as_ushort(__float2half(lo));
  unsigned uhi = (unsigned)__half_as_ushort(__float2half(hi));
  return ulo | (uhi << 16);
}

__device__ __forceinline__ float unpk_(unsigned d, int odd){
  h2t p = __builtin_bit_cast(h2t, d);
  return odd ? (float)p.y : (float)p.x;
}

// ---- init workspace stats + flags + lookup table -----------------------
__global__ void init_kernel(float* ws){
  int i = blockIdx.x*256 + threadIdx.x;
  if (i < 2112) ws[i] = 0.0f;                  // gat stats (64) + bn stats (4*512)
  if (i < 512) ((unsigned*)(ws + 42112))[i] = 0u;  // rec sync flags (4 phases)
  int* table = (int*)(ws + 2112);
  if (i < 40000) table[i] = 0x7fffffff;
}

// ---- gat_output per-channel mean/var reduction (float4 loads) ----------
__global__ void bn_stats_kernel2(const float* __restrict__ gat, float* __restrict__ sums){
  __shared__ float ss[256], sq[256];
  int tid = threadIdx.x;
  int idx = blockIdx.x*256 + tid;
  int stride = gridDim.x*256;
  const int total4 = Bn*Ndim*Gdim/4;
  const float4* g4 = (const float4*)gat;
  float4 s = make_float4(0.f,0.f,0.f,0.f), q = make_float4(0.f,0.f,0.f,0.f);
  for (int i=idx; i<total4; i+=stride){
    float4 v = g4[i];
    s.x+=v.x; s.y+=v.y; s.z+=v.z; s.w+=v.w;
    q.x+=v.x*v.x; q.y+=v.y*v.y; q.z+=v.z*v.z; q.w+=v.w*v.w;
  }
  // threads with equal (tid&7) cover the same 4 channels (g0=4*(tid&7))
  ss[tid]=s.x; sq[tid]=q.x; __syncthreads();
  for (int off=128; off>=8; off>>=1){ if(tid<off){ ss[tid]+=ss[tid+off]; sq[tid]+=sq[tid+off]; } __syncthreads(); }
  if (tid<8){ atomicAdd(&sums[4*tid+0], ss[tid]); atomicAdd(&sums[32+4*tid+0], sq[tid]); }
  __syncthreads();
  ss[tid]=s.y; sq[tid]=q.y; __syncthreads();
  for (int off=128; off>=8; off>>=1){ if(tid<off){ ss[tid]+=ss[tid+off]; sq[tid]+=sq[tid+off]; } __syncthreads(); }
  if (tid<8){ atomicAdd(&sums[4*tid+1], ss[tid]); atomicAdd(&sums[32+4*tid+1], sq[tid]); }
  __syncthreads();
  ss[tid]=s.z; sq[tid]=q.z; __syncthreads();
  for (int off=128; off>=8; off>>=1){ if(tid<off){ ss[tid]+=ss[tid+off]; sq[tid]+=sq[tid+off]; } __syncthreads(); }
  if (tid<8){ atomicAdd(&sums[4*tid+2], ss[tid]); atomicAdd(&sums[32+4*tid+2], sq[tid]); }
  __syncthreads();
  ss[tid]=s.w; sq[tid]=q.w; __syncthreads();
  for (int off=128; off>=8; off>>=1){ if(tid<off){ ss[tid]+=ss[tid+off]; sq[tid]+=sq[tid+off]; } __syncthreads(); }
  if (tid<8){ atomicAdd(&sums[4*tid+3], ss[tid]); atomicAdd(&sums[32+4*tid+3], sq[tid]); }
}

// ---- node id -> first index table --------------------------------------
__global__ void table_kernel(const int* __restrict__ node_ids, int* __restrict__ table){
  int i = blockIdx.x*256 + threadIdx.x;
  if (i < Ndim) atomicMin(&table[node_ids[i]], i);
}

// ---- gather + normalize + concat -> lstm_in packed f16 (BT,32 pairs) ---
__global__ void build_input_kernel(const float* __restrict__ feats, const float* __restrict__ gat,
    const int* __restrict__ row_ids, const int* __restrict__ table, const float* __restrict__ sums,
    const float* __restrict__ bng, const float* __restrict__ bnb, unsigned* __restrict__ out){
  int gt = blockIdx.x*256 + threadIdx.x;     // BT*32 total
  int pos = gt >> 5; int k2 = gt & 31;
  float lo, hi;
  if (k2 < 16){
    float2 v = *(const float2*)(feats + pos*Fdim + 2*k2);
    lo = v.x; hi = v.y;
  } else {
    int g0 = 2*(k2-16);
    int r = row_ids[pos];
    int idx = table[r];
    if (idx < Ndim){
      int b = pos / Tn;
      float2 x = *(const float2*)(gat + (size_t)(b*Ndim + idx)*Gdim + g0);
      const float cnt = (float)(Bn*Ndim);
      float m0 = sums[g0]/cnt,   v0 = sums[32+g0]/cnt - m0*m0;
      float m1 = sums[g0+1]/cnt, v1 = sums[32+g0+1]/cnt - m1*m1;
      lo = (x.x-m0)*bng[g0]*rsqrtf(v0+EPSc) + bnb[g0];
      hi = (x.y-m1)*bng[g0+1]*rsqrtf(v1+EPSc) + bnb[g0+1];
    } else { lo = 0.0f; hi = 0.0f; }
  }
  out[gt] = packh_(lo, hi);
}

// ---- pack+transpose Wih (1024,K) fp32 -> (K/2,1024) f16 pairs ----------
struct TArgs { const float* src[8]; unsigned* dst[8]; int K[8]; };
__global__ void packwih_kernel(TArgs a){
  __shared__ unsigned tile[32][33];
  int mat = blockIdx.y;
  int K = a.K[mat];
  int K2 = K >> 1;
  int ktiles = K2 >> 5;                  // 1 (K=64) or 4 (K=256)
  int tk = blockIdx.x & 3;               // k2-tile
  int tn = blockIdx.x >> 2;              // n-tile 0..31
  if (tk >= ktiles) return;
  const float* src = a.src[mat];
  unsigned* dst = a.dst[mat];
  int tx = threadIdx.x, ty = threadIdx.y;   // 32 x 8
  int n0 = tn*32, k2_0 = tk*32;
  #pragma unroll
  for (int i=0;i<4;i++){
    int nn = ty + 8*i;
    const float* p = src + (size_t)(n0+nn)*K + 2*(k2_0 + tx);
    tile[nn][tx] = packh_(p[0], p[1]);
  }
  __syncthreads();
  #pragma unroll
  for (int i=0;i<4;i++){
    int r = ty + 8*i;  // local k2
    dst[(size_t)(k2_0 + r)*G4 + n0 + tx] = tile[tx][r];
  }
}

// ---- pack Whh (1024,256) fp32 -> f16 pairs, rec v4 unit-split layout ---
// Per matrix 131072 dwords, two 65536-dword halves (u=0/1). Block u,
// thread tid (rgrp=tid&127, ks=tid>>7) owns rows rr=4*rgrp+j (j=0..3),
// row_global = 256*(rr>>7) + 128*u + (rr&127). uint4 ji=j*4+i covers
// pairs base..base+3, base = i<2 ? 8*ks+4*i : 64+8*ks+4*(i-2).
// dword idx (within u half) = (ji*1024 + tid)*4 + e.
struct PkArgs { const float* src[8]; };
__global__ void pack_kernel(PkArgs a, unsigned* __restrict__ dst){
  int gid = blockIdx.x*256 + threadIdx.x;   // 8*131072 total
  int m = gid >> 17;
  int rem = gid & 0x1FFFF;
  int u = rem >> 16;
  int r2 = rem & 0xFFFF;
  int e = r2 & 3;
  int tidv = (r2 >> 2) & 1023;
  int ji = r2 >> 12;          // 0..15
  int j = ji >> 2, i = ji & 3;
  int rgrp = tidv & 127, ks = tidv >> 7;
  int rr = 4*rgrp + j;
  int q = rr >> 7, ul = rr & 127;
  int row = 256*q + 128*u + ul;
  int base = (i < 2) ? (8*ks + 4*i) : (64 + 8*ks + 4*(i-2));
  int p = base + e;
  const float* W = a.src[m];
  dst[gid] = packh_(W[row*256 + 2*p], W[row*256 + 2*p + 1]);
}

// ---- input projection: out(m,1024) = x(m,K) @ WT(K,1024) + bias --------
struct PArgs { const unsigned* x[3]; const unsigned* wt[3]; const float* bias[3]; float* out[3]; int K2; };
__global__ __launch_bounds__(256) void proj_kernel(PArgs a){
  int hd = blockIdx.z;
  int n  = blockIdx.y*256 + threadIdx.x;
  int m0 = blockIdx.x*8;
  int K2 = a.K2;
  const unsigned* xh = a.x[hd] + (size_t)m0*K2;
  const unsigned* wt = a.wt[hd];
  float bv = a.bias[hd][n];
  float acc[8];
  #pragma unroll
  for (int i=0;i<8;i++) acc[i]=bv;
  for (int k2=0;k2<K2;k2+=4){
    unsigned w0 = wt[(size_t)(k2+0)*G4+n];
    unsigned w1 = wt[(size_t)(k2+1)*G4+n];
    unsigned w2 = wt[(size_t)(k2+2)*G4+n];
    unsigned w3 = wt[(size_t)(k2+3)*G4+n];
    #pragma unroll
    for (int i=0;i<8;i++){
      uint4 xv = *(const uint4*)(xh + i*K2 + k2);   // uniform -> s_load_dwordx4
      acc[i]=fdot2_(w0,xv.x,acc[i]); acc[i]=fdot2_(w1,xv.y,acc[i]);
      acc[i]=fdot2_(w2,xv.z,acc[i]); acc[i]=fdot2_(w3,xv.w,acc[i]);
    }
  }
  float* out = a.out[hd] + (size_t)m0*G4 + n;
  #pragma unroll
  for (int i=0;i<8;i++) out[i*G4]=acc[i];
}

// ---- LSTM recurrence v4: 2 CUs per (batch,head), unit-split ------------
// Block u in {0,1} owns units [128u,128u+128) = 512 gate rows, FULL k.
// 1024 threads, 16 uint4 weights fully VGPR-resident (64 regs), zero LDS
// weight streaming. hv: 4 wave-uniform uint4 -> 32 b128 broadcast reads
// per CU-step (vs 224 in r6 -- the ds_read_b128 throughput model).
// Peer h half exchanged via device-scope (XCD-safe) global buffer:
// relaxed agent stores -> barrier (vmcnt drain) -> release flag; consumer
// spins acquire on flag, plain loads after. 2-slot parity, WAR-safe by
// publish-after-read ordering. t=0 skips exchange (h_{-1}=0).
// Co-residency: <=192 blocks of 16 waves, 1 block/CU (VGPR-bound).
struct RArgs { const float* xp[3]; const unsigned* wt[3]; unsigned* outh[3]; unsigned* xch; unsigned* flg; };
__global__ __launch_bounds__(1024) void rec_kernel(RArgs a){
  __shared__ unsigned hp[2][64];       // own h half, packed pairs, 2 slots
  __shared__ float part[8][512];       // 8 k-segments x 512 rows
  int u = blockIdx.x, b = blockIdx.y, hd = blockIdx.z;
  int tid = threadIdx.x;
  int rgrp = tid & 127, ks = tid >> 7;   // ks wave-uniform (64 | 128)
  int pairid = hd*32 + b;
  const float* xp = a.xp[hd] + (size_t)b*Tn*G4 + 128*u;
  const unsigned* wt = a.wt[hd] + ((size_t)u << 16);
  unsigned* outh = a.outh[hd] + (size_t)b*Tn*128 + 64*u;
  unsigned* xme        = a.xch + (size_t)pairid*256 + (size_t)u*128;
  const unsigned* xpr  = a.xch + (size_t)pairid*256 + (size_t)(1-u)*128;
  unsigned* fl = a.flg + pairid*2;

  uint4 w[16];
  #pragma unroll
  for (int ji=0; ji<16; ji++)
    w[ji] = *(const uint4*)(wt + (size_t)((ji<<10) + tid)*4);

  bool epi = (tid < 128);
  int uu = tid & 127;
  float cst = 0.f;

  for (int t=0; t<Tn; t++){
    float xi=0.f, xf=0.f, xg=0.f, xo=0.f;
    if (epi){
      xi = xp[t*G4 + uu];       xf = xp[t*G4 + 256 + uu];
      xg = xp[t*G4 + 512 + uu]; xo = xp[t*G4 + 768 + uu];
    }
    float ac0=0.f, ac1=0.f, ac2=0.f, ac3=0.f;
    if (t){
      int par = (t-1) & 1;
      // acquire peer's h(t-1)
      while (__hip_atomic_load(fl + (1-u), __ATOMIC_ACQUIRE, __HIP_MEMORY_SCOPE_AGENT) < (unsigned)t)
        __builtin_amdgcn_s_sleep(1);
      // peer half first (long latency, covered by own-half dots)
      uint4 pv0 = *(const uint4*)(xpr + par*64 + 8*ks);
      uint4 pv1 = *(const uint4*)(xpr + par*64 + 8*ks + 4);
      // own half from LDS (broadcast)
      uint4 ov0 = *(const uint4*)(&hp[par][8*ks]);
      uint4 ov1 = *(const uint4*)(&hp[par][8*ks + 4]);
      uint4 L0, L1, U0, U1;
      if (u == 0){ L0=ov0; L1=ov1; U0=pv0; U1=pv1; }
      else       { L0=pv0; L1=pv1; U0=ov0; U1=ov1; }
      #define DOT4(A, WV, HV) A=fdot2_((WV).x,(HV).x,A); A=fdot2_((WV).y,(HV).y,A); \
                              A=fdot2_((WV).z,(HV).z,A); A=fdot2_((WV).w,(HV).w,A);
      DOT4(ac0, w[0],  L0) DOT4(ac0, w[1],  L1) DOT4(ac0, w[2],  U0) DOT4(ac0, w[3],  U1)
      DOT4(ac1, w[4],  L0) DOT4(ac1, w[5],  L1) DOT4(ac1, w[6],  U0) DOT4(ac1, w[7],  U1)
      DOT4(ac2, w[8],  L0) DOT4(ac2, w[9],  L1) DOT4(ac2, w[10], U0) DOT4(ac2, w[11], U1)
      DOT4(ac3, w[12], L0) DOT4(ac3, w[13], L1) DOT4(ac3, w[14], U0) DOT4(ac3, w[15], U1)
      #undef DOT4
    }
    *(float4*)&part[ks][4*rgrp] = make_float4(ac0, ac1, ac2, ac3);
    __syncthreads();
    if (epi){
      float gi=xi, gf=xf, gg=xg, go=xo;
      #pragma unroll
      for (int s=0; s<8; s++){
        gi += part[s][uu];       gf += part[s][128+uu];
        gg += part[s][256+uu];   go += part[s][384+uu];
      }
      cst = sigmoidf_(gf)*cst + sigmoidf_(gi)*tanhf_(gg);
      float h = sigmoidf_(go)*tanhf_(cst);
      float hq = __shfl_xor(h, 1);
      if (!(uu & 1)){
        unsigned hh = packh_(h, hq);
        hp[t&1][uu>>1] = hh;
        __hip_atomic_store(xme + (t&1)*64 + (uu>>1), hh, __ATOMIC_RELAXED, __HIP_MEMORY_SCOPE_AGENT);
        outh[t*128 + (uu>>1)] = hh;
      }
    }
    __syncthreads();   // drains all waves' stores (vmcnt) before publish
    if (tid == 0)
      __hip_atomic_store(fl + u, (unsigned)(t+1), __ATOMIC_RELEASE, __HIP_MEMORY_SCOPE_AGENT);
  }
}

// ---- per-feature mean/var stats over (B,T), packed f16 input -----------
struct SArgs { const unsigned* in[3]; float* stats[3]; };
__global__ void stats_kernel(SArgs a){
  int hd = blockIdx.y; int tid = threadIdx.x;
  const unsigned* in = a.in[hd] + (size_t)blockIdx.x*256*128;
  int pu = tid >> 1, odd = tid & 1;
  float s=0.f,q=0.f;
  for (int r=0;r<256;r++){ float v = unpk_(in[r*128 + pu], odd); s+=v; q+=v*v; }
  atomicAdd(&a.stats[hd][tid], s);
  atomicAdd(&a.stats[hd][Hdim+tid], q);
}

// ---- normalize shared output (packed f16 -> packed f16) ----------------
__global__ void norm_kernel(const unsigned* __restrict__ in, const float* __restrict__ stats,
   const float* __restrict__ g, const float* __restrict__ bta, unsigned* __restrict__ outh){
  int i2 = blockIdx.x*256 + threadIdx.x;   // BT*128 total
  int h2i = i2 & 127;
  int h0 = 2*h2i;
  h2t p = __builtin_bit_cast(h2t, in[i2]);
  float m0 = stats[h0]*(1.0f/BT),   v0 = stats[Hdim+h0]*(1.0f/BT) - m0*m0;
  float m1 = stats[h0+1]*(1.0f/BT), v1 = stats[Hdim+h0+1]*(1.0f/BT) - m1*m1;
  float lo = ((float)p.x-m0)*g[h0]*rsqrtf(v0+EPSc) + bta[h0];
  float hi = ((float)p.y-m1)*g[h0+1]*rsqrtf(v1+EPSc) + bta[h0+1];
  outh[i2] = packh_(lo, hi);
}

// ---- final: normalize last step of heads, fc + softmax -----------------
__global__ __launch_bounds__(256) void final_kernel(
  const unsigned* __restrict__ h0, const unsigned* __restrict__ h1, const unsigned* __restrict__ h2,
  const float* __restrict__ stats,    // base ws+S_BN; head hd at (1+hd)*512
  const float* __restrict__ hbg, const float* __restrict__ hbb,
  const float* __restrict__ actW, const float* __restrict__ actB,
  const float* __restrict__ tW, const float* __restrict__ tB,
  const float* __restrict__ rW, const float* __restrict__ rB,
  float* __restrict__ outp){
  __shared__ float v0[Bn*Hdim];
  __shared__ float lg[Bn*Cdim];
  int tid = threadIdx.x;
  for (int i=tid; i<Bn*Hdim; i+=256){
    int b=i>>8, h=i&255;
    float sm = stats[512 + h], sq = stats[512+256+h];
    float mean = sm*(1.0f/BT); float var = sq*(1.0f/BT) - mean*mean;
    float hv = unpk_(h0[(size_t)(b*Tn+63)*128 + (h>>1)], h&1);
    v0[i] = (hv - mean)*hbg[h]*rsqrtf(var+EPSc) + hbb[h];
  }
  __syncthreads();
  for (int i=tid; i<Bn*Cdim; i+=256){
    int b=i>>5, cc=i&31;
    float acc = actB[cc];
    const float* wrow = actW + cc*Hdim;
    const float* vrow = v0 + b*Hdim;
    #pragma unroll 4
    for (int h=0;h<Hdim;h++) acc = fmaf(vrow[h], wrow[h], acc);
    lg[i] = acc;
  }
  __syncthreads();
  if (tid < Bn){
    int b = tid;
    float m = -1e30f;
    #pragma unroll
    for (int cc=0; cc<Cdim; cc++) m = fmaxf(m, lg[b*Cdim+cc]);
    float e[Cdim]; float s = 0.f;
    #pragma unroll
    for (int cc=0; cc<Cdim; cc++){ float ee = __expf(lg[b*Cdim+cc]-m); e[cc]=ee; s+=ee; }
    float inv = 1.0f/s;
    #pragma unroll
    for (int cc=0; cc<Cdim; cc++) outp[b*Cdim+cc] = e[cc]*inv;
  }
  if (tid < 64){
    int b = tid & 31; int w = tid >> 5;
    const unsigned* hh = w ? h2 : h1;
    const float* fw = w ? rW : tW;
    float fb = w ? rB[0] : tB[0];
    int hd = 1 + w;
    float acc = fb;
    for (int h=0; h<Hdim; h++){
      float sm = stats[(1+hd)*512 + h], sq = stats[(1+hd)*512+256+h];
      float mean = sm*(1.0f/BT); float var = sq*(1.0f/BT) - mean*mean;
      float hv = unpk_(hh[(size_t)(b*Tn+63)*128 + (h>>1)], h&1);
      float v = (hv - mean)*hbg[hd*Hdim+h]*rsqrtf(var+EPSc) + hbb[hd*Hdim+h];
      acc = fmaf(v, fw[h], acc);
    }
    outp[1024 + w*32 + b] = acc;
  }
}

extern "C" void kernel_launch(void* const* d_in, const int* in_sizes, int n_in,
                              void* d_out, int out_size, void* d_ws, size_t ws_size,
                              hipStream_t stream){
  const float* data_feats = (const float*)d_in[0];
  const float* gat   = (const float*)d_in[1];
  const int*   row_ids  = (const int*)d_in[2];
  const int*   node_ids = (const int*)d_in[3];
  const float* sWih0 = (const float*)d_in[4];
  const float* sWhh0 = (const float*)d_in[5];
  const float* sb0   = (const float*)d_in[6];
  const float* sWih1 = (const float*)d_in[7];
  const float* sWhh1 = (const float*)d_in[8];
  const float* sb1   = (const float*)d_in[9];
  const float* hWih  = (const float*)d_in[10];
  const float* hWhh  = (const float*)d_in[11];
  const float* hb    = (const float*)d_in[12];
  const float* bng   = (const float*)d_in[13];
  const float* bnb   = (const float*)d_in[14];
  const float* bsg   = (const float*)d_in[15];
  const float* bsb   = (const float*)d_in[16];
  const float* hbg   = (const float*)d_in[17];
  const float* hbb   = (const float*)d_in[18];
  const float* actW  = (const float*)d_in[19];
  const float* actB  = (const float*)d_in[20];
  const float* tW    = (const float*)d_in[21];
  const float* tB    = (const float*)d_in[22];
  const float* rW    = (const float*)d_in[23];
  const float* rB    = (const float*)d_in[24];
  float* ws  = (float*)d_ws;
  float* out = (float*)d_out;

  // workspace layout (float offsets)
  const size_t S_GAT = 0;                         // 64
  const size_t S_BN  = 64;                        // 4*512
  const size_t TABLE = 2112;                      // 40000 ints
  const size_t FLAGS = 42112;                     // 512 uints (4 phase regions)
  const size_t XCH   = 42624;                     // 96 pairs x 256 uints
  const size_t WIHP  = 67200;                     // 8 x 131072 uints (Wih^T f16)
  const size_t PSLOT = 131072;
  const size_t WHHP  = WIHP + 8*PSLOT;            // 8 x 131072 uints (Whh f16, v4 layout)
  const size_t LSTM_INH = WHHP + 8*PSLOT;         // BT*32 uints
  const size_t XPOFF = LSTM_INH + 65536;          // 3 x 2,097,152 fp32
  const size_t BUF0H = XPOFF + 3*2097152;         // BT*128 uints (shared L0 h)
  const size_t BUF1H = BUF0H + 262144;            // BT*128 uints (shared L1 h)
  const size_t BUFNH = BUF1H + 262144;            // BT*128 uints (normalized)
  const size_t HB0H  = BUFNH + 262144;            // 3 x BT*128 uints (heads L0 h)
  const size_t HB1H  = HB0H + 3*262144;           // 3 x BT*128 uints (heads L1 h)

  unsigned* flags = (unsigned*)(ws + FLAGS);
  unsigned* xch   = (unsigned*)(ws + XCH);

  init_kernel<<<157,256,0,stream>>>(ws);
  bn_stats_kernel2<<<1024,256,0,stream>>>(gat, ws+S_GAT);
  table_kernel<<<(Ndim+255)/256,256,0,stream>>>(node_ids, (int*)(ws+TABLE));
  build_input_kernel<<<256,256,0,stream>>>(data_feats, gat, row_ids, (int*)(ws+TABLE),
                                           ws+S_GAT, bng, bnb, (unsigned*)(ws+LSTM_INH));

  // Wih pack+transpose to f16 [k2][1024]
  unsigned* wih = (unsigned*)(ws + WIHP);
  TArgs ta;
  ta.src[0]=sWih0; ta.K[0]=64;
  ta.src[1]=sWih1; ta.K[1]=256;
  for (int hd=0; hd<3; hd++) for (int l=0;l<2;l++){
    ta.src[2+hd*2+l] = hWih + (size_t)(hd*2+l)*G4*Hdim; ta.K[2+hd*2+l] = 256;
  }
  for (int i=0;i<8;i++) ta.dst[i] = wih + (size_t)i*PSLOT;
  packwih_kernel<<<dim3(128,8),dim3(32,8),0,stream>>>(ta);

  // Whh f16 pack (rec v4 unit-split layout)
  unsigned* whh = (unsigned*)(ws + WHHP);
  PkArgs pka;
  pka.src[0]=sWhh0; pka.src[1]=sWhh1;
  for (int hd=0; hd<3; hd++) for (int l=0;l<2;l++)
    pka.src[2+hd*2+l] = hWhh + (size_t)(hd*2+l)*G4*Hdim;
  pack_kernel<<<4096,256,0,stream>>>(pka, whh);

  PArgs pa; RArgs ra; SArgs sa;
  // shared layer 0
  pa.K2=32; pa.x[0]=(unsigned*)(ws+LSTM_INH); pa.wt[0]=wih+0*PSLOT; pa.bias[0]=sb0; pa.out[0]=ws+XPOFF;
  proj_kernel<<<dim3(256,4,1),256,0,stream>>>(pa);
  ra.xp[0]=ws+XPOFF; ra.wt[0]=whh+0*PSLOT; ra.outh[0]=(unsigned*)(ws+BUF0H);
  ra.xch=xch; ra.flg=flags+0;
  rec_kernel<<<dim3(2,32,1),1024,0,stream>>>(ra);
  // shared layer 1
  pa.K2=128; pa.x[0]=(unsigned*)(ws+BUF0H); pa.wt[0]=wih+1*PSLOT; pa.bias[0]=sb1; pa.out[0]=ws+XPOFF;
  proj_kernel<<<dim3(256,4,1),256,0,stream>>>(pa);
  ra.xp[0]=ws+XPOFF; ra.wt[0]=whh+1*PSLOT; ra.outh[0]=(unsigned*)(ws+BUF1H);
  ra.xch=xch; ra.flg=flags+64;
  rec_kernel<<<dim3(2,32,1),1024,0,stream>>>(ra);
  // shared batchnorm
  sa.in[0]=(unsigned*)(ws+BUF1H); sa.stats[0]=ws+S_BN;
  stats_kernel<<<dim3(8,1),256,0,stream>>>(sa);
  norm_kernel<<<1024,256,0,stream>>>((unsigned*)(ws+BUF1H), ws+S_BN, bsg, bsb, (unsigned*)(ws+BUFNH));
  // heads layer 0
  pa.K2=128;
  for (int hd=0;hd<3;hd++){
    pa.x[hd]=(unsigned*)(ws+BUFNH); pa.wt[hd]=wih+(size_t)(2+hd*2)*PSLOT; pa.bias[hd]=hb + (size_t)(hd*2)*G4;
    pa.out[hd]=ws+XPOFF+(size_t)hd*2097152;
  }
  proj_kernel<<<dim3(256,4,3),256,0,stream>>>(pa);
  for (int hd=0;hd<3;hd++){
    ra.xp[hd]=ws+XPOFF+(size_t)hd*2097152; ra.wt[hd]=whh+(size_t)(2+hd*2)*PSLOT;
    ra.outh[hd]=(unsigned*)(ws+HB0H)+(size_t)hd*262144;
  }
  ra.xch=xch; ra.flg=flags+128;
  rec_kernel<<<dim3(2,32,3),1024,0,stream>>>(ra);
  // heads layer 1
  for (int hd=0;hd<3;hd++){
    pa.x[hd]=(unsigned*)(ws+HB0H)+(size_t)hd*262144; pa.wt[hd]=wih+(size_t)(2+hd*2+1)*PSLOT;
    pa.bias[hd]=hb + (size_t)(hd*2+1)*G4;
    pa.out[hd]=ws+XPOFF+(size_t)hd*2097152;
  }
  proj_kernel<<<dim3(256,4,3),256,0,stream>>>(pa);
  for (int hd=0;hd<3;hd++){
    ra.xp[hd]=ws+XPOFF+(size_t)hd*2097152; ra.wt[hd]=whh+(size_t)(2+hd*2+1)*PSLOT;
    ra.outh[hd]=(unsigned*)(ws+HB1H)+(size_t)hd*262144;
  }
  ra.xch=xch; ra.flg=flags+320;
  rec_kernel<<<dim3(2,32,3),1024,0,stream>>>(ra);
  // heads batchnorm stats
  for (int hd=0;hd<3;hd++){ sa.in[hd]=(unsigned*)(ws+HB1H)+(size_t)hd*262144; sa.stats[hd]=ws+S_BN+(size_t)(1+hd)*512; }
  stats_kernel<<<dim3(8,3),256,0,stream>>>(sa);
  // final outputs
  final_kernel<<<1,256,0,stream>>>((unsigned*)(ws+HB1H), (unsigned*)(ws+HB1H)+262144, (unsigned*)(ws+HB1H)+2*262144,
                                   ws+S_BN, hbg, hbb, actW, actB, tW, tB, rW, rB, out);
}